// Round 9
// baseline (211.966 us; speedup 1.0000x reference)
//
#include <hip/hip_runtime.h>
#include <stdint.h>

typedef unsigned int u32;
typedef int v4i  __attribute__((ext_vector_type(4)));
typedef int v16i __attribute__((ext_vector_type(16)));

#define K_MSG   1024
#define N_CODE  2048
#define NB      32768

// ---------------- pack b -> i8: [NB][1024] int32 -> [NB][1024] i8 -----------
__global__ void pack_bi8(const int* __restrict__ b, u32* __restrict__ bi8) {
    const int nthr = gridDim.x * blockDim.x;
    int idx = blockIdx.x * blockDim.x + threadIdx.x;
    const int ndw = NB * K_MSG / 4;                 // output dwords
    for (; idx < ndw; idx += nthr) {
        int4 v = *(const int4*)(b + (size_t)idx * 4);
        bi8[idx] = (u32)(v.x & 1) | ((u32)(v.y & 1) << 8) |
                   ((u32)(v.z & 1) << 16) | ((u32)(v.w & 1) << 24);
    }
}

// ------------- pack G -> i8 transposed: GT8[j][k] = G[k][j] & 1 -------------
__global__ void pack_gT8(const int* __restrict__ G, u32* __restrict__ gt8) {
    int idx = blockIdx.x * blockDim.x + threadIdx.x;   // 524288 total
    const int j  = idx & (N_CODE - 1);
    const int kq = idx >> 11;                          // 0..255
    u32 p = 0;
#pragma unroll
    for (int i = 0; i < 4; ++i) {
        int v = G[(size_t)(kq * 4 + i) * N_CODE + j];
        p |= (u32)(v & 1) << (8 * i);
    }
    gt8[(size_t)j * (K_MSG / 4) + kq] = p;
}

// ---------------- barrier-free MFMA GEMM ------------------------------------
// Block = 4 waves; A-panel (64 rows x 1024 B) staged ONCE in LDS (swizzled),
// one __syncthreads, then 32 k-steps with NO barriers: 2 ds_read_b128 (A) +
// 4 global dwordx4 (B, L2-resident 2MB) + 8 mfma_i32_32x32x32_i8 per wave,
// 1-deep cur/nxt register pipeline. Wave tile 64x128 (acc 128 VGPR).
// XCD-swizzled block ids: each XCD owns disjoint M-panels -> A HBM-read once.

#define MFMA_SET(a0_, a1_, b0_, b1_, b2_, b3_) do {                               \
    acc[0][0] = __builtin_amdgcn_mfma_i32_32x32x32_i8(a0_, b0_, acc[0][0], 0,0,0); \
    acc[0][1] = __builtin_amdgcn_mfma_i32_32x32x32_i8(a0_, b1_, acc[0][1], 0,0,0); \
    acc[0][2] = __builtin_amdgcn_mfma_i32_32x32x32_i8(a0_, b2_, acc[0][2], 0,0,0); \
    acc[0][3] = __builtin_amdgcn_mfma_i32_32x32x32_i8(a0_, b3_, acc[0][3], 0,0,0); \
    acc[1][0] = __builtin_amdgcn_mfma_i32_32x32x32_i8(a1_, b0_, acc[1][0], 0,0,0); \
    acc[1][1] = __builtin_amdgcn_mfma_i32_32x32x32_i8(a1_, b1_, acc[1][1], 0,0,0); \
    acc[1][2] = __builtin_amdgcn_mfma_i32_32x32x32_i8(a1_, b2_, acc[1][2], 0,0,0); \
    acc[1][3] = __builtin_amdgcn_mfma_i32_32x32x32_i8(a1_, b3_, acc[1][3], 0,0,0); \
} while (0)

#define LOAD_SET(a0_, a1_, b0_, b1_, b2_, b3_, s_) do {                           \
    int ao = lr * 1024 + ((((s_) * 32) + hi * 16) ^ axor);                        \
    a0_ = *(const v4i*)(As + ao);                                                 \
    a1_ = *(const v4i*)(As + ao + 32768);                                         \
    b0_ = *(const v4i*)(bp0 + (s_) * 32);                                         \
    b1_ = *(const v4i*)(bp1 + (s_) * 32);                                         \
    b2_ = *(const v4i*)(bp2 + (s_) * 32);                                         \
    b3_ = *(const v4i*)(bp3 + (s_) * 32);                                         \
} while (0)

__global__ __launch_bounds__(256, 2) void gemm_i8(const char* __restrict__ bi8,
                                                  const char* __restrict__ gt8,
                                                  int* __restrict__ out) {
    __shared__ __align__(16) char As[64 * 1024];    // 64 KB

    const int t   = threadIdx.x;
    // bijective XCD swizzle (2048 blocks % 8 == 0): XCD k owns M-panels
    // [k*64, (k+1)*64) -> disjoint A per XCD, A fetched from HBM once.
    const int bid = blockIdx.x;
    const int swz = (bid & 7) * 256 + (bid >> 3);
    const int m0  = (swz >> 2) * 64;
    const int n0  = (swz & 3) * 512;

    const int w  = t >> 6, lane = t & 63, lr = lane & 31, hi = lane >> 5;

    // ---- stage A panel (contiguous 64 KB) into LDS, XOR-swizzled ----
    {
        const char* src = bi8 + (size_t)m0 * 1024;
#pragma unroll
        for (int i = 0; i < 16; ++i) {
            uint4 v = *(const uint4*)(src + i * 4096 + t * 16);   // 1KB/wave, coalesced
            int row = i * 4 + (t >> 6);
            int off = (t & 63) * 16;
            *(uint4*)(As + row * 1024 + (off ^ ((row & 7) << 4))) = v;
        }
    }
    __syncthreads();    // the only barrier

    const char* bp0 = gt8 + (size_t)(n0 + w * 128 + lr) * 1024 + hi * 16;
    const char* bp1 = bp0 + 32 * 1024;
    const char* bp2 = bp0 + 64 * 1024;
    const char* bp3 = bp0 + 96 * 1024;
    const int axor = (lr & 7) << 4;

    v16i acc[2][4] = {};
    v4i a0c, a1c, b0c, b1c, b2c, b3c;
    v4i a0n, a1n, b0n, b1n, b2n, b3n;

    LOAD_SET(a0c, a1c, b0c, b1c, b2c, b3c, 0);
#pragma unroll 1
    for (int s = 0; s < 32; s += 2) {
        LOAD_SET(a0n, a1n, b0n, b1n, b2n, b3n, s + 1);   // prefetch odd step
        MFMA_SET(a0c, a1c, b0c, b1c, b2c, b3c);
        if (s + 2 < 32)
            LOAD_SET(a0c, a1c, b0c, b1c, b2c, b3c, s + 2); // prefetch even step
        MFMA_SET(a0n, a1n, b0n, b1n, b2n, b3n);
    }

    // ---- epilogue: parity = acc & 1 (C/D map: col=lane&31, row=(r&3)+8*(r>>2)+4*hi)
#pragma unroll
    for (int mi = 0; mi < 2; ++mi) {
#pragma unroll
        for (int ni = 0; ni < 4; ++ni) {
            const int cbase = n0 + w * 128 + ni * 32 + lr;
            const int rbase = m0 + mi * 32 + 4 * hi;
#pragma unroll
            for (int r = 0; r < 16; ++r) {
                const int row = rbase + (r & 3) + 8 * (r >> 2);
                out[(size_t)row * N_CODE + cbase] = acc[mi][ni][r] & 1;
            }
        }
    }
}

// ---------------- fallback (only if ws too small) ---------------------------
__global__ void encode_naive(const int* __restrict__ b, const int* __restrict__ G,
                             int* __restrict__ out) {
    size_t idx = (size_t)blockIdx.x * blockDim.x + threadIdx.x;
    size_t total = (size_t)NB * N_CODE;
    if (idx >= total) return;
    int i = (int)(idx / N_CODE);
    int j = (int)(idx % N_CODE);
    int acc = 0;
    for (int k = 0; k < K_MSG; ++k)
        acc ^= b[(size_t)i * K_MSG + k] & G[(size_t)k * N_CODE + j];
    out[idx] = acc & 1;
}

extern "C" void kernel_launch(void* const* d_in, const int* in_sizes, int n_in,
                              void* d_out, int out_size, void* d_ws, size_t ws_size,
                              hipStream_t stream) {
    const int* b = (const int*)d_in[0];
    const int* G = (const int*)d_in[1];
    int* out = (int*)d_out;

    const size_t bi8_bytes = (size_t)NB * K_MSG;          // 32 MiB
    const size_t gt8_bytes = (size_t)N_CODE * K_MSG;      // 2 MiB

    if (ws_size < bi8_bytes + gt8_bytes) {
        size_t total = (size_t)NB * N_CODE;
        encode_naive<<<(unsigned)((total + 255) / 256), 256, 0, stream>>>(b, G, out);
        return;
    }

    char* bi8 = (char*)d_ws;
    char* gt8 = (char*)d_ws + bi8_bytes;

    pack_bi8<<<2048, 256, 0, stream>>>(b, (u32*)bi8);
    pack_gT8<<<2048, 256, 0, stream>>>(G, (u32*)gt8);

    gemm_i8<<<2048, 256, 0, stream>>>(bi8, gt8, out);   // (NB/64)*(N_CODE/512)
}

// Round 10
// 150.058 us; speedup vs baseline: 1.4126x; 1.4126x over previous
//
#include <hip/hip_runtime.h>
#include <stdint.h>

typedef unsigned int u32;
typedef int v4i  __attribute__((ext_vector_type(4)));
typedef int v16i __attribute__((ext_vector_type(16)));

#define K_MSG   1024
#define N_CODE  2048
#define NB      32768

// ---------------- pack b -> i8: [NB][1024] int32 -> [NB][1024] i8 -----------
__global__ void pack_bi8(const int* __restrict__ b, u32* __restrict__ bi8) {
    const int nthr = gridDim.x * blockDim.x;
    int idx = blockIdx.x * blockDim.x + threadIdx.x;
    const int ndw = NB * K_MSG / 4;                 // output dwords
    for (; idx < ndw; idx += nthr) {
        int4 v = *(const int4*)(b + (size_t)idx * 4);
        bi8[idx] = (u32)(v.x & 1) | ((u32)(v.y & 1) << 8) |
                   ((u32)(v.z & 1) << 16) | ((u32)(v.w & 1) << 24);
    }
}

// ------------- pack G -> fragment-major i8 B ---------------------------------
// BF tile = one MFMA B-fragment (32 cols x 32 k) = 1024 B, stored in LANE order:
//   offset = ((jb*32 + kb)*1024) + hi*512 + jr*16 + (k & 15)
// where jb=j>>5, jr=j&31, kb=k>>5, hi=(k&31)>>4.  A wave's frag load is then
// base + lane*16 -> one fully-coalesced dwordx4.
__global__ void pack_gBF(const int* __restrict__ G, u32* __restrict__ bf) {
    int idx = blockIdx.x * blockDim.x + threadIdx.x;   // 524288
    const int j  = idx & (N_CODE - 1);                 // coalesced G reads
    const int kq = idx >> 11;                          // dword of k: 0..255
    u32 p = 0;
#pragma unroll
    for (int i = 0; i < 4; ++i) {
        int v = G[(size_t)(kq * 4 + i) * N_CODE + j];
        p |= (u32)(v & 1) << (8 * i);
    }
    const int jb = j >> 5, jr = j & 31;
    const int kb = kq >> 3, hi = (kq >> 2) & 1, b4 = kq & 3;
    bf[(size_t)(jb * 32 + kb) * 256 + hi * 128 + jr * 4 + b4] = p;
}

// ---------------- barrier-free MFMA GEMM ------------------------------------
// Block = 4 waves; A-panel (64 rows x 1024 B) staged ONCE in LDS (swizzled),
// one __syncthreads, then 32 k-steps, NO barriers. B frags read fragment-major
// from L2 (contiguous 1KB/load). 2-deep pipeline: 4 named register sets.

#define MFMA_SET(sfx) do {                                                         \
    acc[0][0] = __builtin_amdgcn_mfma_i32_32x32x32_i8(a0##sfx, b0##sfx, acc[0][0], 0,0,0); \
    acc[0][1] = __builtin_amdgcn_mfma_i32_32x32x32_i8(a0##sfx, b1##sfx, acc[0][1], 0,0,0); \
    acc[0][2] = __builtin_amdgcn_mfma_i32_32x32x32_i8(a0##sfx, b2##sfx, acc[0][2], 0,0,0); \
    acc[0][3] = __builtin_amdgcn_mfma_i32_32x32x32_i8(a0##sfx, b3##sfx, acc[0][3], 0,0,0); \
    acc[1][0] = __builtin_amdgcn_mfma_i32_32x32x32_i8(a1##sfx, b0##sfx, acc[1][0], 0,0,0); \
    acc[1][1] = __builtin_amdgcn_mfma_i32_32x32x32_i8(a1##sfx, b1##sfx, acc[1][1], 0,0,0); \
    acc[1][2] = __builtin_amdgcn_mfma_i32_32x32x32_i8(a1##sfx, b2##sfx, acc[1][2], 0,0,0); \
    acc[1][3] = __builtin_amdgcn_mfma_i32_32x32x32_i8(a1##sfx, b3##sfx, acc[1][3], 0,0,0); \
} while (0)

#define LOAD_SET(sfx, s_) do {                                                     \
    int ao_ = lr * 1024 + ((((s_) * 32) + hi * 16) ^ axor);                        \
    a0##sfx = *(const v4i*)(As + ao_);                                             \
    a1##sfx = *(const v4i*)(As + ao_ + 32768);                                     \
    b0##sfx = *(const v4i*)(bp0 + (size_t)(s_) * 1024);                            \
    b1##sfx = *(const v4i*)(bp1 + (size_t)(s_) * 1024);                            \
    b2##sfx = *(const v4i*)(bp2 + (size_t)(s_) * 1024);                            \
    b3##sfx = *(const v4i*)(bp3 + (size_t)(s_) * 1024);                            \
} while (0)

__global__ __launch_bounds__(256, 2) void gemm_i8(const char* __restrict__ bi8,
                                                  const char* __restrict__ bf,
                                                  int* __restrict__ out) {
    __shared__ __align__(16) char As[64 * 1024];    // 64 KB

    const int t   = threadIdx.x;
    // bijective XCD swizzle (2048 % 8 == 0): XCD k owns disjoint M-panels.
    const int bid = blockIdx.x;
    const int swz = (bid & 7) * 256 + (bid >> 3);
    const int m0  = (swz >> 2) * 64;
    const int n0  = (swz & 3) * 512;

    const int w  = t >> 6, lane = t & 63, lr = lane & 31, hi = lane >> 5;

    // ---- stage A panel (contiguous 64 KB) into LDS, XOR-swizzled ----
    {
        const char* src = bi8 + (size_t)m0 * 1024;
#pragma unroll
        for (int i = 0; i < 16; ++i) {
            uint4 v = *(const uint4*)(src + i * 4096 + t * 16);   // coalesced
            int row = i * 4 + (t >> 6);
            int off = (t & 63) * 16;
            *(uint4*)(As + row * 1024 + (off ^ ((row & 7) << 4))) = v;
        }
    }
    __syncthreads();    // the only barrier

    // fragment-major B bases: colblk = n0/32 + w*4 + ni, frag stride 32KB
    const char* bp0 = bf + ((size_t)(n0 >> 5) + w * 4) * 32768 + lane * 16;
    const char* bp1 = bp0 + 32768;
    const char* bp2 = bp0 + 65536;
    const char* bp3 = bp0 + 98304;
    const int axor = (lr & 7) << 4;

    v16i acc[2][4] = {};
    v4i a0A, a1A, b0A, b1A, b2A, b3A;
    v4i a0B, a1B, b0B, b1B, b2B, b3B;
    v4i a0C, a1C, b0C, b1C, b2C, b3C;
    v4i a0D, a1D, b0D, b1D, b2D, b3D;

    LOAD_SET(A, 0);
    LOAD_SET(B, 1);
#pragma unroll 1
    for (int s = 0; s < 32; s += 4) {
        LOAD_SET(C, s + 2);
        LOAD_SET(D, s + 3);
        MFMA_SET(A);
        MFMA_SET(B);
        if (s + 4 < 32) {
            LOAD_SET(A, s + 4);
            LOAD_SET(B, s + 5);
        }
        MFMA_SET(C);
        MFMA_SET(D);
    }

    // ---- epilogue: parity = acc & 1 (C/D: col=lane&31, row=(r&3)+8*(r>>2)+4*hi)
#pragma unroll
    for (int mi = 0; mi < 2; ++mi) {
#pragma unroll
        for (int ni = 0; ni < 4; ++ni) {
            const int cbase = n0 + w * 128 + ni * 32 + lr;
            const int rbase = m0 + mi * 32 + 4 * hi;
#pragma unroll
            for (int r = 0; r < 16; ++r) {
                const int row = rbase + (r & 3) + 8 * (r >> 2);
                out[(size_t)row * N_CODE + cbase] = acc[mi][ni][r] & 1;
            }
        }
    }
}

// ---------------- fallback (only if ws too small) ---------------------------
__global__ void encode_naive(const int* __restrict__ b, const int* __restrict__ G,
                             int* __restrict__ out) {
    size_t idx = (size_t)blockIdx.x * blockDim.x + threadIdx.x;
    size_t total = (size_t)NB * N_CODE;
    if (idx >= total) return;
    int i = (int)(idx / N_CODE);
    int j = (int)(idx % N_CODE);
    int acc = 0;
    for (int k = 0; k < K_MSG; ++k)
        acc ^= b[(size_t)i * K_MSG + k] & G[(size_t)k * N_CODE + j];
    out[idx] = acc & 1;
}

extern "C" void kernel_launch(void* const* d_in, const int* in_sizes, int n_in,
                              void* d_out, int out_size, void* d_ws, size_t ws_size,
                              hipStream_t stream) {
    const int* b = (const int*)d_in[0];
    const int* G = (const int*)d_in[1];
    int* out = (int*)d_out;

    const size_t bi8_bytes = (size_t)NB * K_MSG;          // 32 MiB
    const size_t bf_bytes  = (size_t)N_CODE * K_MSG;      // 2 MiB

    if (ws_size < bi8_bytes + bf_bytes) {
        size_t total = (size_t)NB * N_CODE;
        encode_naive<<<(unsigned)((total + 255) / 256), 256, 0, stream>>>(b, G, out);
        return;
    }

    char* bi8 = (char*)d_ws;
    char* bf  = (char*)d_ws + bi8_bytes;

    pack_bi8<<<2048, 256, 0, stream>>>(b, (u32*)bi8);
    pack_gBF<<<2048, 256, 0, stream>>>(G, (u32*)bf);

    gemm_i8<<<2048, 256, 0, stream>>>(bi8, bf, out);   // (NB/64)*(N_CODE/512)
}